// Round 22
// baseline (90.503 us; speedup 1.0000x reference)
//
#include <hip/hip_runtime.h>

// TopKGate via split-precision f16 MFMA (no fp32 MFMA on CDNA4):
//   x = xh + xl/4096, w = wh + wl/4096 (f16 planes, lo pre-scaled x4096)
//   logits = xh*wh + (xh*wl' + xl'*wh)/4096
// R22 = R20's K-split (grid 2048 = 1024 tiles x 2 K-halves, 6 blocks/CU,
// 24 waves/CU) with R17/R19's pipeline discipline: NBUF=3, ONE barrier per
// chunk, counted WVM(2) (never drain mid-loop). Partials summed by the
// R20-verified finish kernel (softmax/top-2/aux).

typedef __attribute__((ext_vector_type(8))) _Float16 half8;
typedef __attribute__((ext_vector_type(4))) float f32x4;

constexpr int DD  = 2048;
constexpr int EE  = 64;
constexpr int BM  = 16;          // tokens per tile
constexpr int BK  = 128;         // k per staged chunk
constexpr int NCH = 8;           // chunks per K-half (K=1024)

#define WVM(N) asm volatile("s_waitcnt vmcnt(" #N ")" ::: "memory")
#define BAR()  asm volatile("s_barrier" ::: "memory")

// ---- pre-kernel (R15-proven): Wg[2048][64] -> fragment-linear wF ----
// wF[(kc*8 + t*2 + p)*512 + l*8 + j] = plane_p( Wg[kc*32+(l>>4)*8+j][t*16+(l&15)] )
__global__ __launch_bounds__(256) void wsplit_kernel(
    const float* __restrict__ Wg, _Float16* __restrict__ wF)
{
    __shared__ float xl[32][65];
    const int tid = threadIdx.x;
    const int kc  = blockIdx.x;          // 64 blocks, 32 k's each
    const int k0  = kc * 32;
#pragma unroll
    for (int r = 0; r < 2; ++r) {
        int slot = tid + r * 256;        // float4 slots 0..511
        int row = slot >> 4, c4 = (slot & 15) << 2;
        *(float4*)&xl[row][c4] = *(const float4*)&Wg[(size_t)(k0 + row) * EE + c4];
    }
    __syncthreads();
    const int t = tid >> 6, l = tid & 63;
    const int e  = t * 16 + (l & 15);
    const int kl = (l >> 4) * 8;
    half8 hh, ll;
#pragma unroll
    for (int j = 0; j < 8; ++j) {
        float v = xl[kl + j][e];
        _Float16 h = (_Float16)v;
        hh[j] = h;
        ll[j] = (_Float16)((v - (float)h) * 4096.f);
    }
    const size_t base = (size_t)(kc * 8 + t * 2) * 512 + (size_t)l * 8;
    *(half8*)&wF[base]       = hh;       // hi plane
    *(half8*)&wF[base + 512] = ll;       // lo plane
}

__global__ __launch_bounds__(256, 4) void gate_kernel(
    const float* __restrict__ x, const _Float16* __restrict__ wF,
    float* __restrict__ partial)
{
    __shared__ __align__(16) union {
        float xs[3][BM][BK];             // 24 KB staging (3 bufs)
        float red[4][BM][65];            // 16.6 KB kq-reduction
    } sm;

    const int tid  = threadIdx.x;
    const int kq   = tid >> 6;           // wave = K-quarter of chunk (32 k's)
    const int lane = tid & 63;
    const int tile = blockIdx.x >> 1;    // token tile 0..1023
    const int kb   = blockIdx.x & 1;     // K-half 0..1
    const size_t tok0 = (size_t)tile * BM;
    const float* xg = x + tok0 * DD + kb * 1024;

    // ---- x staging: 2 dwordx4 DMA per thread per chunk, 32B source-XOR ----
    auto stageX = [&](int buf, int c) {
#pragma unroll
        for (int r = 0; r < 2; ++r) {
            int slot = tid + r * 256;            // float4 slot 0..511
            int row  = slot >> 5;                // 0..15
            int cb   = (slot & 31) << 4;         // dest byte 0..511 (linear)
            int sb   = cb ^ ((row & 7) << 5);    // source-swizzled byte
            __builtin_amdgcn_global_load_lds(
                xg + (size_t)row * DD + c * BK + (sb >> 2),
                &sm.xs[buf][row][cb >> 2], 16, 0, 0);
        }
    };

    f32x4 aH[4], aL[4];
#pragma unroll
    for (int t = 0; t < 4; ++t) {
        aH[t] = (f32x4){0.f, 0.f, 0.f, 0.f};
        aL[t] = (f32x4){0.f, 0.f, 0.f, 0.f};
    }

    const int rrow = lane & 15;          // token row
    const int rb   = (kq * 128 + ((lane >> 4) * 32)) ^ ((rrow & 7) << 5);

    auto compute = [&](int buf, int c) {
        // this wave's 32-k slice: global slice index kb*32 + c*4 + kq
        const _Float16* wb = wF + (size_t)(kb * 32 + c * 4 + kq) * 4096
                                + (size_t)lane * 8;
        half8 wh[4], wl[4];
#pragma unroll
        for (int t = 0; t < 4; ++t) {
            wh[t] = *(const half8*)(wb + (t * 2) * 512);
            wl[t] = *(const half8*)(wb + (t * 2 + 1) * 512);
        }
        // x fragment: one 8-float read, split once
        const float* p = (const float*)((const char*)&sm.xs[buf][rrow][0] + rb);
        float4 xa = *(const float4*)p;
        float4 xb = *(const float4*)(p + 4);
        half8 ah, al;
        {
            float v;
            v = xa.x; { _Float16 h=(_Float16)v; ah[0]=h; al[0]=(_Float16)((v-(float)h)*4096.f); }
            v = xa.y; { _Float16 h=(_Float16)v; ah[1]=h; al[1]=(_Float16)((v-(float)h)*4096.f); }
            v = xa.z; { _Float16 h=(_Float16)v; ah[2]=h; al[2]=(_Float16)((v-(float)h)*4096.f); }
            v = xa.w; { _Float16 h=(_Float16)v; ah[3]=h; al[3]=(_Float16)((v-(float)h)*4096.f); }
            v = xb.x; { _Float16 h=(_Float16)v; ah[4]=h; al[4]=(_Float16)((v-(float)h)*4096.f); }
            v = xb.y; { _Float16 h=(_Float16)v; ah[5]=h; al[5]=(_Float16)((v-(float)h)*4096.f); }
            v = xb.z; { _Float16 h=(_Float16)v; ah[6]=h; al[6]=(_Float16)((v-(float)h)*4096.f); }
            v = xb.w; { _Float16 h=(_Float16)v; ah[7]=h; al[7]=(_Float16)((v-(float)h)*4096.f); }
        }
#pragma unroll
        for (int t = 0; t < 4; ++t) {
            aH[t] = __builtin_amdgcn_mfma_f32_16x16x32_f16(ah, wh[t], aH[t], 0, 0, 0);
            aL[t] = __builtin_amdgcn_mfma_f32_16x16x32_f16(ah, wl[t], aL[t], 0, 0, 0);
            aL[t] = __builtin_amdgcn_mfma_f32_16x16x32_f16(al, wh[t], aL[t], 0, 0, 0);
        }
    };

    // prologue: 2 stages in flight; NBUF=3, one barrier per chunk:
    // stage(c+2) writes the buf consumed by compute(c-1), which every wave
    // passed before BAR(c). Counted waits: never drain mid-loop.
    stageX(0, 0);
    stageX(1, 1);
#pragma unroll 1
    for (int c = 0; c < NCH; ++c) {
        if (c < NCH - 1) { WVM(2); } else { WVM(0); }  // own stage(c) landed
        BAR();                                   // all waves' stage(c) visible
        compute(c % 3, c);
        if (c + 2 < NCH) stageX((c + 2) % 3, c + 2);
    }

    // ---- reduce 4 kq-partials in LDS (m89-verified C layout) ----
    __syncthreads();                             // before union reuse
    const float inv = 1.f / 4096.f;
#pragma unroll
    for (int e = 0; e < 4; ++e) {
        const int row = (lane >> 4) * 4 + e;     // token 0..15
#pragma unroll
        for (int t = 0; t < 4; ++t)
            sm.red[kq][row][t * 16 + (lane & 15)] = aH[t][e] + aL[t][e] * inv;
    }
    __syncthreads();

    // wave kq writes rows [kq*4, kq*4+4) of this block's partial
    float* pb = partial + (size_t)blockIdx.x * (BM * EE);
#pragma unroll
    for (int rr = 0; rr < 4; ++rr) {
        const int row = kq * 4 + rr;
        float v = (sm.red[0][row][lane] + sm.red[1][row][lane])
                + (sm.red[2][row][lane] + sm.red[3][row][lane]);
        pb[row * EE + lane] = v;
    }
}

// ---- finish: sum 2 K-half partials, softmax/top-2, aux block partials ----
__global__ __launch_bounds__(256) void finish_kernel(
    const float* __restrict__ partial,
    float* __restrict__ gate_out, float* __restrict__ idx_out,
    float* __restrict__ pSum, float* __restrict__ pCnt)
{
    const int tid  = threadIdx.x;
    const int wv   = tid >> 6;       // 0..3
    const int lane = tid & 63;       // = expert id
    __shared__ float auxsm[2][4][64];

    float sumP_acc = 0.f;
    float cnt_acc  = 0.f;
#pragma unroll 1
    for (int tt = 0; tt < 16; ++tt) {
        const size_t t    = (size_t)blockIdx.x * 64 + wv * 16 + tt;
        const size_t tile = t >> 4;
        const int    row  = (int)(t & 15);
        const float* pb = partial + tile * 2 * (BM * EE) + row * EE;
        float v = pb[lane] + pb[BM * EE + lane];   // half0 + half1

        float m = v;
#pragma unroll
        for (int off = 32; off; off >>= 1) m = fmaxf(m, __shfl_xor(m, off, 64));
        float p = expf(v - m);
        float s = p;
#pragma unroll
        for (int off = 32; off; off >>= 1) s += __shfl_xor(s, off, 64);
        float prob = p / s;
        sumP_acc += prob;

        // top-1 (ties -> lowest index, matches lax.top_k)
        float bv = prob; int bi = lane;
#pragma unroll
        for (int off = 32; off; off >>= 1) {
            float ov = __shfl_xor(bv, off, 64);
            int   oi = __shfl_xor(bi, off, 64);
            if (ov > bv || (ov == bv && oi < bi)) { bv = ov; bi = oi; }
        }
        // top-2
        float v2 = (lane == bi) ? -1.f : prob;
        float bv2 = v2; int bi2 = lane;
#pragma unroll
        for (int off = 32; off; off >>= 1) {
            float ov = __shfl_xor(bv2, off, 64);
            int   oi = __shfl_xor(bi2, off, 64);
            if (ov > bv2 || (ov == bv2 && oi < bi2)) { bv2 = ov; bi2 = oi; }
        }

        float denom = bv + bv2;
        float g1 = bv / denom, g2 = bv2 / denom;
        float g = (lane == bi) ? g1 : ((lane == bi2) ? g2 : 0.f);
        gate_out[t * EE + lane] = g;
        if (lane == 0) {
            idx_out[2 * t]     = (float)bi;
            idx_out[2 * t + 1] = (float)bi2;
        }
        cnt_acc += (lane == bi)  ? 1.f : 0.f;
        cnt_acc += (lane == bi2) ? 1.f : 0.f;
    }

    auxsm[0][wv][lane] = sumP_acc;
    auxsm[1][wv][lane] = cnt_acc;
    __syncthreads();
    if (wv == 0) {
        float sp = auxsm[0][0][lane] + auxsm[0][1][lane]
                 + auxsm[0][2][lane] + auxsm[0][3][lane];
        float cc = auxsm[1][0][lane] + auxsm[1][1][lane]
                 + auxsm[1][2][lane] + auxsm[1][3][lane];
        pSum[(size_t)blockIdx.x * 64 + lane] = sp;
        pCnt[(size_t)blockIdx.x * 64 + lane] = cc;
    }
}

// ---- aux final: 1 block over 256 partial rows ----
__global__ __launch_bounds__(256) void aux2_kernel(
    const float* __restrict__ pSum, const float* __restrict__ pCnt,
    float* __restrict__ aux_out, float scale)
{
    const int tid  = threadIdx.x;
    const int wv   = tid >> 6;       // 0..3
    const int lane = tid & 63;       // = expert id
    __shared__ float smem[2][4][64];

    float sp = 0.f, cc = 0.f;
#pragma unroll 1
    for (int b = wv; b < 256; b += 4) {
        sp += pSum[(size_t)b * 64 + lane];
        cc += pCnt[(size_t)b * 64 + lane];
    }
    smem[0][wv][lane] = sp;
    smem[1][wv][lane] = cc;
    __syncthreads();
    if (wv == 0) {
        float SP = smem[0][0][lane] + smem[0][1][lane]
                 + smem[0][2][lane] + smem[0][3][lane];
        float CC = smem[1][0][lane] + smem[1][1][lane]
                 + smem[1][2][lane] + smem[1][3][lane];
        float prod = SP * CC;
#pragma unroll
        for (int off = 32; off; off >>= 1) prod += __shfl_xor(prod, off, 64);
        if (lane == 0) aux_out[0] = prod * scale;
    }
}

extern "C" void kernel_launch(void* const* d_in, const int* in_sizes, int n_in,
                              void* d_out, int out_size, void* d_ws, size_t ws_size,
                              hipStream_t stream) {
    const float* x  = (const float*)d_in[0];
    const float* Wg = (const float*)d_in[1];
    const int T = in_sizes[0] / DD;          // 16384

    float* out      = (float*)d_out;
    float* gate_out = out;                                // T*64
    float* idx_out  = out + (size_t)T * EE;               // T*2 (as float)
    float* aux_out  = idx_out + (size_t)T * 2;            // 1

    const int ntiles = T / BM;                            // 1024
    _Float16* wF   = (_Float16*)d_ws;                     // 512 KB frag-linear
    float* partial = (float*)(wF + (size_t)64 * 8 * 512); // 2048*1024 f32 = 8 MB
    float* pSum    = partial + (size_t)ntiles * 2 * BM * EE;
    float* pCnt    = pSum + 256 * 64;

    wsplit_kernel<<<64, 256, 0, stream>>>(Wg, wF);
    gate_kernel<<<ntiles * 2, 256, 0, stream>>>(x, wF, partial);
    finish_kernel<<<T / 64, 256, 0, stream>>>(partial, gate_out, idx_out,
                                              pSum, pCnt);
    const float scale = (float)EE / ((float)T * (float)T);
    aux2_kernel<<<1, 256, 0, stream>>>(pSum, pCnt, aux_out, scale);
}

// Round 23
// 63.161 us; speedup vs baseline: 1.4329x; 1.4329x over previous
//
#include <hip/hip_runtime.h>

// TopKGate via split-precision f16 MFMA (no fp32 MFMA on CDNA4):
//   x = xh + xl/4096, w = wh + wl/4096 (f16 planes, lo pre-scaled x4096)
//   logits = xh*wh + (xh*wl' + xl'*wh)/4096
// R23 = R19 skeleton + CROSS-ITERATION REGISTER PREFETCH OF W: named ping-pong
// half8 regs (wA0..7 / wB0..7) loaded one iteration ahead (issued after
// compute(c), pinned by the asm WVM/BAR clobbers -> cannot sink). compute()
// has zero vmem ops. Steady-state WVM(2). Grid 1024, BM=16, NCH=16, NBUF=3.

typedef __attribute__((ext_vector_type(8))) _Float16 half8;
typedef __attribute__((ext_vector_type(4))) float f32x4;

constexpr int DD  = 2048;
constexpr int EE  = 64;
constexpr int BM  = 16;          // tokens per block
constexpr int BK  = 128;         // k per staged chunk (each wave: 32-k quarter)
constexpr int NCH = DD / BK;     // 16 chunks

#define WVM(N) asm volatile("s_waitcnt vmcnt(" #N ")" ::: "memory")
#define BAR()  asm volatile("s_barrier" ::: "memory")

// ---- pre-kernel (R15-proven): Wg[2048][64] -> fragment-linear wF ----
// wF[(kc*8 + t*2 + p)*512 + l*8 + j] = plane_p( Wg[kc*32+(l>>4)*8+j][t*16+(l&15)] )
__global__ __launch_bounds__(256) void wsplit_kernel(
    const float* __restrict__ Wg, _Float16* __restrict__ wF)
{
    __shared__ float xl[32][65];
    const int tid = threadIdx.x;
    const int kc  = blockIdx.x;          // 64 blocks, 32 k's each
    const int k0  = kc * 32;
#pragma unroll
    for (int r = 0; r < 2; ++r) {
        int slot = tid + r * 256;        // float4 slots 0..511
        int row = slot >> 4, c4 = (slot & 15) << 2;
        *(float4*)&xl[row][c4] = *(const float4*)&Wg[(size_t)(k0 + row) * EE + c4];
    }
    __syncthreads();
    const int t = tid >> 6, l = tid & 63;
    const int e  = t * 16 + (l & 15);
    const int kl = (l >> 4) * 8;
    half8 hh, ll;
#pragma unroll
    for (int j = 0; j < 8; ++j) {
        float v = xl[kl + j][e];
        _Float16 h = (_Float16)v;
        hh[j] = h;
        ll[j] = (_Float16)((v - (float)h) * 4096.f);
    }
    const size_t base = (size_t)(kc * 8 + t * 2) * 512 + (size_t)l * 8;
    *(half8*)&wF[base]       = hh;       // hi plane
    *(half8*)&wF[base + 512] = ll;       // lo plane
}

__global__ __launch_bounds__(256, 4) void gate_kernel(
    const float* __restrict__ x, const _Float16* __restrict__ wF,
    float* __restrict__ gate_out, float* __restrict__ idx_out,
    float* __restrict__ pSum, float* __restrict__ pCnt)
{
    __shared__ __align__(16) union {
        float xs[3][BM][BK];                               // 24 KB staging
        struct { float red[4][BM][68]; float auxsm[2][4][64]; } ep; // 19.5 KB
    } sm;

    const int tid  = threadIdx.x;
    const int kq   = tid >> 6;           // wave = K-quarter of chunk (32 k's)
    const int lane = tid & 63;
    const size_t tok0 = (size_t)blockIdx.x * BM;
    const float* xg = x + tok0 * DD;

    // ---- x staging: 2 dwordx4 DMA per thread per chunk, 32B source-XOR ----
    auto stageX = [&](int buf, int c) {
#pragma unroll
        for (int r = 0; r < 2; ++r) {
            int slot = tid + r * 256;            // float4 slot 0..511
            int row  = slot >> 5;                // 0..15
            int cb   = (slot & 31) << 4;         // dest byte 0..511
            int sb   = cb ^ ((row & 7) << 5);    // source-swizzled byte
            __builtin_amdgcn_global_load_lds(
                xg + (size_t)row * DD + c * BK + (sb >> 2),
                &sm.xs[buf][row][cb >> 2], 16, 0, 0);
        }
    };

    f32x4 aH[4], aL[4];
#pragma unroll
    for (int t = 0; t < 4; ++t) {
        aH[t] = (f32x4){0.f, 0.f, 0.f, 0.f};
        aL[t] = (f32x4){0.f, 0.f, 0.f, 0.f};
    }

    const int rrow = lane & 15;          // token row
    const int rb   = (kq * 128 + ((lane >> 4) * 32)) ^ ((rrow & 7) << 5);

    // named w fragment registers (rule #20: no runtime-indexed arrays)
    half8 wA0, wA1, wA2, wA3, wA4, wA5, wA6, wA7;
    half8 wB0, wB1, wB2, wB3, wB4, wB5, wB6, wB7;

#define LOADW(W, c)                                                            \
    do {                                                                       \
        const _Float16* wb_ = wF + (size_t)((c) * 4 + kq) * 4096               \
                                 + (size_t)lane * 8;                           \
        W##0 = *(const half8*)(wb_ + 0 * 512);                                 \
        W##1 = *(const half8*)(wb_ + 1 * 512);                                 \
        W##2 = *(const half8*)(wb_ + 2 * 512);                                 \
        W##3 = *(const half8*)(wb_ + 3 * 512);                                 \
        W##4 = *(const half8*)(wb_ + 4 * 512);                                 \
        W##5 = *(const half8*)(wb_ + 5 * 512);                                 \
        W##6 = *(const half8*)(wb_ + 6 * 512);                                 \
        W##7 = *(const half8*)(wb_ + 7 * 512);                                 \
    } while (0)

#define COMPUTE(buf, W)                                                        \
    do {                                                                       \
        const float* p = (const float*)((const char*)&sm.xs[buf][rrow][0] + rb); \
        float4 xa = *(const float4*)p;                                         \
        float4 xb = *(const float4*)(p + 4);                                   \
        half8 ah, al; float v;                                                 \
        v = xa.x; { _Float16 h=(_Float16)v; ah[0]=h; al[0]=(_Float16)((v-(float)h)*4096.f); } \
        v = xa.y; { _Float16 h=(_Float16)v; ah[1]=h; al[1]=(_Float16)((v-(float)h)*4096.f); } \
        v = xa.z; { _Float16 h=(_Float16)v; ah[2]=h; al[2]=(_Float16)((v-(float)h)*4096.f); } \
        v = xa.w; { _Float16 h=(_Float16)v; ah[3]=h; al[3]=(_Float16)((v-(float)h)*4096.f); } \
        v = xb.x; { _Float16 h=(_Float16)v; ah[4]=h; al[4]=(_Float16)((v-(float)h)*4096.f); } \
        v = xb.y; { _Float16 h=(_Float16)v; ah[5]=h; al[5]=(_Float16)((v-(float)h)*4096.f); } \
        v = xb.z; { _Float16 h=(_Float16)v; ah[6]=h; al[6]=(_Float16)((v-(float)h)*4096.f); } \
        v = xb.w; { _Float16 h=(_Float16)v; ah[7]=h; al[7]=(_Float16)((v-(float)h)*4096.f); } \
        aH[0] = __builtin_amdgcn_mfma_f32_16x16x32_f16(ah, W##0, aH[0], 0, 0, 0); \
        aL[0] = __builtin_amdgcn_mfma_f32_16x16x32_f16(ah, W##1, aL[0], 0, 0, 0); \
        aL[0] = __builtin_amdgcn_mfma_f32_16x16x32_f16(al, W##0, aL[0], 0, 0, 0); \
        aH[1] = __builtin_amdgcn_mfma_f32_16x16x32_f16(ah, W##2, aH[1], 0, 0, 0); \
        aL[1] = __builtin_amdgcn_mfma_f32_16x16x32_f16(ah, W##3, aL[1], 0, 0, 0); \
        aL[1] = __builtin_amdgcn_mfma_f32_16x16x32_f16(al, W##2, aL[1], 0, 0, 0); \
        aH[2] = __builtin_amdgcn_mfma_f32_16x16x32_f16(ah, W##4, aH[2], 0, 0, 0); \
        aL[2] = __builtin_amdgcn_mfma_f32_16x16x32_f16(ah, W##5, aL[2], 0, 0, 0); \
        aL[2] = __builtin_amdgcn_mfma_f32_16x16x32_f16(al, W##4, aL[2], 0, 0, 0); \
        aH[3] = __builtin_amdgcn_mfma_f32_16x16x32_f16(ah, W##6, aH[3], 0, 0, 0); \
        aL[3] = __builtin_amdgcn_mfma_f32_16x16x32_f16(ah, W##7, aL[3], 0, 0, 0); \
        aL[3] = __builtin_amdgcn_mfma_f32_16x16x32_f16(al, W##6, aL[3], 0, 0, 0); \
    } while (0)

    // prologue: LOADW(0) first (oldest), then 2 stages in flight
    LOADW(wA, 0);
    stageX(0, 0);
    stageX(1, 1);

    // steady state, per iter c: queue = {stage(c)[2], LOADW(c)[8], stage(c+1)[2]}
    // -> WVM(2) drains stage(c)+LOADW(c), leaves stage(c+1). WVM(0) at c=15.
#pragma unroll 1
    for (int cc = 0; cc < NCH; cc += 2) {
        // even chunk c = cc (uses wA)
        WVM(2);
        BAR();
        COMPUTE(cc % 3, wA);
        LOADW(wB, cc + 1);                       // cc+1 <= 15 always
        if (cc + 2 < NCH) stageX((cc + 2) % 3, cc + 2);
        // odd chunk c = cc+1 (uses wB)
        if (cc < NCH - 2) { WVM(2); } else { WVM(0); }
        BAR();
        COMPUTE((cc + 1) % 3, wB);
        if (cc + 2 < NCH) LOADW(wA, cc + 2);
        if (cc + 3 < NCH) stageX((cc + 3) % 3, cc + 3);
    }
#undef LOADW
#undef COMPUTE

    // ---- K-partials -> LDS (m89-verified C layout), combine planes ----
    __syncthreads();
    const float inv = 1.f / 4096.f;
#pragma unroll
    for (int e = 0; e < 4; ++e) {
        const int row = (lane >> 4) * 4 + e;     // token 0..15
#pragma unroll
        for (int t = 0; t < 4; ++t)
            sm.ep.red[kq][row][t * 16 + (lane & 15)] = aH[t][e] + aL[t][e] * inv;
    }
    __syncthreads();

    // ---- epilogue: wave kq -> tokens [kq*4, kq*4+4); lane = expert ----
    float sumP_acc = 0.f;
    float cnt_acc  = 0.f;
#pragma unroll 1
    for (int tt = 0; tt < 4; ++tt) {
        const int tl = kq * 4 + tt;
        const size_t t = tok0 + tl;
        float v = (sm.ep.red[0][tl][lane] + sm.ep.red[1][tl][lane])
                + (sm.ep.red[2][tl][lane] + sm.ep.red[3][tl][lane]);

        float m = v;
#pragma unroll
        for (int off = 32; off; off >>= 1) m = fmaxf(m, __shfl_xor(m, off, 64));
        float p = expf(v - m);
        float s = p;
#pragma unroll
        for (int off = 32; off; off >>= 1) s += __shfl_xor(s, off, 64);
        float prob = p / s;
        sumP_acc += prob;

        // top-1 (ties -> lowest index, matches lax.top_k)
        float bv = prob; int bi = lane;
#pragma unroll
        for (int off = 32; off; off >>= 1) {
            float ov = __shfl_xor(bv, off, 64);
            int   oi = __shfl_xor(bi, off, 64);
            if (ov > bv || (ov == bv && oi < bi)) { bv = ov; bi = oi; }
        }
        // top-2
        float v2 = (lane == bi) ? -1.f : prob;
        float bv2 = v2; int bi2 = lane;
#pragma unroll
        for (int off = 32; off; off >>= 1) {
            float ov = __shfl_xor(bv2, off, 64);
            int   oi = __shfl_xor(bi2, off, 64);
            if (ov > bv2 || (ov == bv2 && oi < bi2)) { bv2 = ov; bi2 = oi; }
        }

        float denom = bv + bv2;
        float g1 = bv / denom, g2 = bv2 / denom;
        float g = (lane == bi) ? g1 : ((lane == bi2) ? g2 : 0.f);
        gate_out[t * EE + lane] = g;
        if (lane == 0) {
            idx_out[2 * t]     = (float)bi;
            idx_out[2 * t + 1] = (float)bi2;
        }
        cnt_acc += (lane == bi)  ? 1.f : 0.f;
        cnt_acc += (lane == bi2) ? 1.f : 0.f;
    }

    // ---- per-block aux partials (deterministic) ----
    sm.ep.auxsm[0][kq][lane] = sumP_acc;
    sm.ep.auxsm[1][kq][lane] = cnt_acc;
    __syncthreads();
    if (kq == 0) {
        float sp = 0.f, c2 = 0.f;
#pragma unroll
        for (int w = 0; w < 4; ++w) {
            sp += sm.ep.auxsm[0][w][lane];
            c2 += sm.ep.auxsm[1][w][lane];
        }
        pSum[(size_t)blockIdx.x * 64 + lane] = sp;
        pCnt[(size_t)blockIdx.x * 64 + lane] = c2;
    }
}

// ---- aux stage 1: 64 blocks, each reduces 16 source rows (all experts) ----
__global__ __launch_bounds__(256) void aux1_kernel(
    const float* __restrict__ pSum, const float* __restrict__ pCnt,
    float* __restrict__ p2Sum, float* __restrict__ p2Cnt)
{
    const int tid  = threadIdx.x;
    const int wv   = tid >> 6;       // 0..3
    const int lane = tid & 63;       // = expert id
    __shared__ float smem[2][4][64];

    const int r0 = blockIdx.x * 16 + wv * 4;
    float sp = 0.f, cc = 0.f;
#pragma unroll
    for (int u = 0; u < 4; ++u) {
        sp += pSum[(size_t)(r0 + u) * 64 + lane];
        cc += pCnt[(size_t)(r0 + u) * 64 + lane];
    }
    smem[0][wv][lane] = sp;
    smem[1][wv][lane] = cc;
    __syncthreads();
    if (wv == 0) {
        float SP = smem[0][0][lane] + smem[0][1][lane]
                 + smem[0][2][lane] + smem[0][3][lane];
        float CC = smem[1][0][lane] + smem[1][1][lane]
                 + smem[1][2][lane] + smem[1][3][lane];
        p2Sum[(size_t)blockIdx.x * 64 + lane] = SP;
        p2Cnt[(size_t)blockIdx.x * 64 + lane] = CC;
    }
}

// ---- aux stage 2: 1 block over 64 partials ----
__global__ __launch_bounds__(256) void aux2_kernel(
    const float* __restrict__ p2Sum, const float* __restrict__ p2Cnt,
    float* __restrict__ aux_out, float scale)
{
    const int tid  = threadIdx.x;
    const int wv   = tid >> 6;       // 0..3
    const int lane = tid & 63;       // = expert id
    __shared__ float smem[2][4][64];

    float sp = 0.f, cc = 0.f;
#pragma unroll 1
    for (int b = wv * 16; b < wv * 16 + 16; ++b) {
        sp += p2Sum[(size_t)b * 64 + lane];
        cc += p2Cnt[(size_t)b * 64 + lane];
    }
    smem[0][wv][lane] = sp;
    smem[1][wv][lane] = cc;
    __syncthreads();
    if (wv == 0) {
        float SP = smem[0][0][lane] + smem[0][1][lane]
                 + smem[0][2][lane] + smem[0][3][lane];
        float CC = smem[1][0][lane] + smem[1][1][lane]
                 + smem[1][2][lane] + smem[1][3][lane];
        float prod = SP * CC;
#pragma unroll
        for (int off = 32; off; off >>= 1) prod += __shfl_xor(prod, off, 64);
        if (lane == 0) aux_out[0] = prod * scale;
    }
}

extern "C" void kernel_launch(void* const* d_in, const int* in_sizes, int n_in,
                              void* d_out, int out_size, void* d_ws, size_t ws_size,
                              hipStream_t stream) {
    const float* x  = (const float*)d_in[0];
    const float* Wg = (const float*)d_in[1];
    const int T = in_sizes[0] / DD;          // 16384

    float* out      = (float*)d_out;
    float* gate_out = out;                                // T*64
    float* idx_out  = out + (size_t)T * EE;               // T*2 (as float)
    float* aux_out  = idx_out + (size_t)T * 2;            // 1

    const int nblocks = T / BM;                           // 1024
    _Float16* wF = (_Float16*)d_ws;                       // 512 KB frag-linear
    float* pSum  = (float*)(wF + (size_t)64 * 8 * 512);   // 1024*64
    float* pCnt  = pSum + (size_t)nblocks * 64;           // 1024*64
    float* p2Sum = pCnt + (size_t)nblocks * 64;           // 64*64
    float* p2Cnt = p2Sum + 64 * 64;                       // 64*64

    wsplit_kernel<<<64, 256, 0, stream>>>(Wg, wF);
    gate_kernel<<<nblocks, 256, 0, stream>>>(x, wF, gate_out, idx_out, pSum, pCnt);

    const float scale = (float)EE / ((float)T * (float)T);
    aux1_kernel<<<64, 256, 0, stream>>>(pSum, pCnt, p2Sum, p2Cnt);
    aux2_kernel<<<1, 256, 0, stream>>>(p2Sum, p2Cnt, aux_out, scale);
}

// Round 24
// 62.205 us; speedup vs baseline: 1.4549x; 1.0154x over previous
//
#include <hip/hip_runtime.h>

// TopKGate via split-precision f16 MFMA (no fp32 MFMA on CDNA4):
//   x = xh + xl/4096, w = wh + wl/4096 (f16 planes, lo pre-scaled x4096)
//   logits = xh*wh + (xh*wl' + xl'*wh)/4096
// R24 = R23 (cross-iteration register prefetch of w, zero vmem in compute)
// + amdgpu_waves_per_eu(4,4): pin the 128-VGPR budget so the ~118-reg
// pipeline fits WITHOUT spilling (R23: compiler squeezed to 64 VGPR ->
// wA/wB spilled, WRITE_SIZE 4.7->20.5 MB). Grid 1024, BM=16, NCH=16, NBUF=3.

typedef __attribute__((ext_vector_type(8))) _Float16 half8;
typedef __attribute__((ext_vector_type(4))) float f32x4;

constexpr int DD  = 2048;
constexpr int EE  = 64;
constexpr int BM  = 16;          // tokens per block
constexpr int BK  = 128;         // k per staged chunk (each wave: 32-k quarter)
constexpr int NCH = DD / BK;     // 16 chunks

#define WVM(N) asm volatile("s_waitcnt vmcnt(" #N ")" ::: "memory")
#define BAR()  asm volatile("s_barrier" ::: "memory")

// ---- pre-kernel (R15-proven): Wg[2048][64] -> fragment-linear wF ----
// wF[(kc*8 + t*2 + p)*512 + l*8 + j] = plane_p( Wg[kc*32+(l>>4)*8+j][t*16+(l&15)] )
__global__ __launch_bounds__(256) void wsplit_kernel(
    const float* __restrict__ Wg, _Float16* __restrict__ wF)
{
    __shared__ float xl[32][65];
    const int tid = threadIdx.x;
    const int kc  = blockIdx.x;          // 64 blocks, 32 k's each
    const int k0  = kc * 32;
#pragma unroll
    for (int r = 0; r < 2; ++r) {
        int slot = tid + r * 256;        // float4 slots 0..511
        int row = slot >> 4, c4 = (slot & 15) << 2;
        *(float4*)&xl[row][c4] = *(const float4*)&Wg[(size_t)(k0 + row) * EE + c4];
    }
    __syncthreads();
    const int t = tid >> 6, l = tid & 63;
    const int e  = t * 16 + (l & 15);
    const int kl = (l >> 4) * 8;
    half8 hh, ll;
#pragma unroll
    for (int j = 0; j < 8; ++j) {
        float v = xl[kl + j][e];
        _Float16 h = (_Float16)v;
        hh[j] = h;
        ll[j] = (_Float16)((v - (float)h) * 4096.f);
    }
    const size_t base = (size_t)(kc * 8 + t * 2) * 512 + (size_t)l * 8;
    *(half8*)&wF[base]       = hh;       // hi plane
    *(half8*)&wF[base + 512] = ll;       // lo plane
}

__global__ void __attribute__((amdgpu_flat_work_group_size(256, 256),
                               amdgpu_waves_per_eu(4, 4)))
gate_kernel(
    const float* __restrict__ x, const _Float16* __restrict__ wF,
    float* __restrict__ gate_out, float* __restrict__ idx_out,
    float* __restrict__ pSum, float* __restrict__ pCnt)
{
    __shared__ __align__(16) union {
        float xs[3][BM][BK];                               // 24 KB staging
        struct { float red[4][BM][68]; float auxsm[2][4][64]; } ep; // 19.5 KB
    } sm;

    const int tid  = threadIdx.x;
    const int kq   = tid >> 6;           // wave = K-quarter of chunk (32 k's)
    const int lane = tid & 63;
    const size_t tok0 = (size_t)blockIdx.x * BM;
    const float* xg = x + tok0 * DD;

    // ---- x staging: 2 dwordx4 DMA per thread per chunk, 32B source-XOR ----
    auto stageX = [&](int buf, int c) {
#pragma unroll
        for (int r = 0; r < 2; ++r) {
            int slot = tid + r * 256;            // float4 slot 0..511
            int row  = slot >> 5;                // 0..15
            int cb   = (slot & 31) << 4;         // dest byte 0..511
            int sb   = cb ^ ((row & 7) << 5);    // source-swizzled byte
            __builtin_amdgcn_global_load_lds(
                xg + (size_t)row * DD + c * BK + (sb >> 2),
                &sm.xs[buf][row][cb >> 2], 16, 0, 0);
        }
    };

    f32x4 aH[4], aL[4];
#pragma unroll
    for (int t = 0; t < 4; ++t) {
        aH[t] = (f32x4){0.f, 0.f, 0.f, 0.f};
        aL[t] = (f32x4){0.f, 0.f, 0.f, 0.f};
    }

    const int rrow = lane & 15;          // token row
    const int rb   = (kq * 128 + ((lane >> 4) * 32)) ^ ((rrow & 7) << 5);

    // named w fragment registers (rule #20: no runtime-indexed arrays)
    half8 wA0, wA1, wA2, wA3, wA4, wA5, wA6, wA7;
    half8 wB0, wB1, wB2, wB3, wB4, wB5, wB6, wB7;

#define LOADW(W, c)                                                            \
    do {                                                                       \
        const _Float16* wb_ = wF + (size_t)((c) * 4 + kq) * 4096               \
                                 + (size_t)lane * 8;                           \
        W##0 = *(const half8*)(wb_ + 0 * 512);                                 \
        W##1 = *(const half8*)(wb_ + 1 * 512);                                 \
        W##2 = *(const half8*)(wb_ + 2 * 512);                                 \
        W##3 = *(const half8*)(wb_ + 3 * 512);                                 \
        W##4 = *(const half8*)(wb_ + 4 * 512);                                 \
        W##5 = *(const half8*)(wb_ + 5 * 512);                                 \
        W##6 = *(const half8*)(wb_ + 6 * 512);                                 \
        W##7 = *(const half8*)(wb_ + 7 * 512);                                 \
    } while (0)

#define COMPUTE(buf, W)                                                        \
    do {                                                                       \
        const float* p = (const float*)((const char*)&sm.xs[buf][rrow][0] + rb); \
        float4 xa = *(const float4*)p;                                         \
        float4 xb = *(const float4*)(p + 4);                                   \
        half8 ah, al; float v;                                                 \
        v = xa.x; { _Float16 h=(_Float16)v; ah[0]=h; al[0]=(_Float16)((v-(float)h)*4096.f); } \
        v = xa.y; { _Float16 h=(_Float16)v; ah[1]=h; al[1]=(_Float16)((v-(float)h)*4096.f); } \
        v = xa.z; { _Float16 h=(_Float16)v; ah[2]=h; al[2]=(_Float16)((v-(float)h)*4096.f); } \
        v = xa.w; { _Float16 h=(_Float16)v; ah[3]=h; al[3]=(_Float16)((v-(float)h)*4096.f); } \
        v = xb.x; { _Float16 h=(_Float16)v; ah[4]=h; al[4]=(_Float16)((v-(float)h)*4096.f); } \
        v = xb.y; { _Float16 h=(_Float16)v; ah[5]=h; al[5]=(_Float16)((v-(float)h)*4096.f); } \
        v = xb.z; { _Float16 h=(_Float16)v; ah[6]=h; al[6]=(_Float16)((v-(float)h)*4096.f); } \
        v = xb.w; { _Float16 h=(_Float16)v; ah[7]=h; al[7]=(_Float16)((v-(float)h)*4096.f); } \
        aH[0] = __builtin_amdgcn_mfma_f32_16x16x32_f16(ah, W##0, aH[0], 0, 0, 0); \
        aL[0] = __builtin_amdgcn_mfma_f32_16x16x32_f16(ah, W##1, aL[0], 0, 0, 0); \
        aL[0] = __builtin_amdgcn_mfma_f32_16x16x32_f16(al, W##0, aL[0], 0, 0, 0); \
        aH[1] = __builtin_amdgcn_mfma_f32_16x16x32_f16(ah, W##2, aH[1], 0, 0, 0); \
        aL[1] = __builtin_amdgcn_mfma_f32_16x16x32_f16(ah, W##3, aL[1], 0, 0, 0); \
        aL[1] = __builtin_amdgcn_mfma_f32_16x16x32_f16(al, W##2, aL[1], 0, 0, 0); \
        aH[2] = __builtin_amdgcn_mfma_f32_16x16x32_f16(ah, W##4, aH[2], 0, 0, 0); \
        aL[2] = __builtin_amdgcn_mfma_f32_16x16x32_f16(ah, W##5, aL[2], 0, 0, 0); \
        aL[2] = __builtin_amdgcn_mfma_f32_16x16x32_f16(al, W##4, aL[2], 0, 0, 0); \
        aH[3] = __builtin_amdgcn_mfma_f32_16x16x32_f16(ah, W##6, aH[3], 0, 0, 0); \
        aL[3] = __builtin_amdgcn_mfma_f32_16x16x32_f16(ah, W##7, aL[3], 0, 0, 0); \
        aL[3] = __builtin_amdgcn_mfma_f32_16x16x32_f16(al, W##6, aL[3], 0, 0, 0); \
    } while (0)

    // prologue: LOADW(0) first (oldest), then 2 stages in flight
    LOADW(wA, 0);
    stageX(0, 0);
    stageX(1, 1);

    // steady state, per iter c: queue = {stage(c)[2], LOADW(c)[8], stage(c+1)[2]}
    // -> WVM(2) drains stage(c)+LOADW(c), leaves stage(c+1). WVM(0) at c=15.
#pragma unroll 1
    for (int cc = 0; cc < NCH; cc += 2) {
        // even chunk c = cc (uses wA)
        WVM(2);
        BAR();
        COMPUTE(cc % 3, wA);
        LOADW(wB, cc + 1);                       // cc+1 <= 15 always
        if (cc + 2 < NCH) stageX((cc + 2) % 3, cc + 2);
        // odd chunk c = cc+1 (uses wB)
        if (cc < NCH - 2) { WVM(2); } else { WVM(0); }
        BAR();
        COMPUTE((cc + 1) % 3, wB);
        if (cc + 2 < NCH) LOADW(wA, cc + 2);
        if (cc + 3 < NCH) stageX((cc + 3) % 3, cc + 3);
    }
#undef LOADW
#undef COMPUTE

    // ---- K-partials -> LDS (m89-verified C layout), combine planes ----
    __syncthreads();
    const float inv = 1.f / 4096.f;
#pragma unroll
    for (int e = 0; e < 4; ++e) {
        const int row = (lane >> 4) * 4 + e;     // token 0..15
#pragma unroll
        for (int t = 0; t < 4; ++t)
            sm.ep.red[kq][row][t * 16 + (lane & 15)] = aH[t][e] + aL[t][e] * inv;
    }
    __syncthreads();

    // ---- epilogue: wave kq -> tokens [kq*4, kq*4+4); lane = expert ----
    float sumP_acc = 0.f;
    float cnt_acc  = 0.f;
#pragma unroll 1
    for (int tt = 0; tt < 4; ++tt) {
        const int tl = kq * 4 + tt;
        const size_t t = tok0 + tl;
        float v = (sm.ep.red[0][tl][lane] + sm.ep.red[1][tl][lane])
                + (sm.ep.red[2][tl][lane] + sm.ep.red[3][tl][lane]);

        float m = v;
#pragma unroll
        for (int off = 32; off; off >>= 1) m = fmaxf(m, __shfl_xor(m, off, 64));
        float p = expf(v - m);
        float s = p;
#pragma unroll
        for (int off = 32; off; off >>= 1) s += __shfl_xor(s, off, 64);
        float prob = p / s;
        sumP_acc += prob;

        // top-1 (ties -> lowest index, matches lax.top_k)
        float bv = prob; int bi = lane;
#pragma unroll
        for (int off = 32; off; off >>= 1) {
            float ov = __shfl_xor(bv, off, 64);
            int   oi = __shfl_xor(bi, off, 64);
            if (ov > bv || (ov == bv && oi < bi)) { bv = ov; bi = oi; }
        }
        // top-2
        float v2 = (lane == bi) ? -1.f : prob;
        float bv2 = v2; int bi2 = lane;
#pragma unroll
        for (int off = 32; off; off >>= 1) {
            float ov = __shfl_xor(bv2, off, 64);
            int   oi = __shfl_xor(bi2, off, 64);
            if (ov > bv2 || (ov == bv2 && oi < bi2)) { bv2 = ov; bi2 = oi; }
        }

        float denom = bv + bv2;
        float g1 = bv / denom, g2 = bv2 / denom;
        float g = (lane == bi) ? g1 : ((lane == bi2) ? g2 : 0.f);
        gate_out[t * EE + lane] = g;
        if (lane == 0) {
            idx_out[2 * t]     = (float)bi;
            idx_out[2 * t + 1] = (float)bi2;
        }
        cnt_acc += (lane == bi)  ? 1.f : 0.f;
        cnt_acc += (lane == bi2) ? 1.f : 0.f;
    }

    // ---- per-block aux partials (deterministic) ----
    sm.ep.auxsm[0][kq][lane] = sumP_acc;
    sm.ep.auxsm[1][kq][lane] = cnt_acc;
    __syncthreads();
    if (kq == 0) {
        float sp = 0.f, c2 = 0.f;
#pragma unroll
        for (int w = 0; w < 4; ++w) {
            sp += sm.ep.auxsm[0][w][lane];
            c2 += sm.ep.auxsm[1][w][lane];
        }
        pSum[(size_t)blockIdx.x * 64 + lane] = sp;
        pCnt[(size_t)blockIdx.x * 64 + lane] = c2;
    }
}

// ---- aux stage 1: 64 blocks, each reduces 16 source rows (all experts) ----
__global__ __launch_bounds__(256) void aux1_kernel(
    const float* __restrict__ pSum, const float* __restrict__ pCnt,
    float* __restrict__ p2Sum, float* __restrict__ p2Cnt)
{
    const int tid  = threadIdx.x;
    const int wv   = tid >> 6;       // 0..3
    const int lane = tid & 63;       // = expert id
    __shared__ float smem[2][4][64];

    const int r0 = blockIdx.x * 16 + wv * 4;
    float sp = 0.f, cc = 0.f;
#pragma unroll
    for (int u = 0; u < 4; ++u) {
        sp += pSum[(size_t)(r0 + u) * 64 + lane];
        cc += pCnt[(size_t)(r0 + u) * 64 + lane];
    }
    smem[0][wv][lane] = sp;
    smem[1][wv][lane] = cc;
    __syncthreads();
    if (wv == 0) {
        float SP = smem[0][0][lane] + smem[0][1][lane]
                 + smem[0][2][lane] + smem[0][3][lane];
        float CC = smem[1][0][lane] + smem[1][1][lane]
                 + smem[1][2][lane] + smem[1][3][lane];
        p2Sum[(size_t)blockIdx.x * 64 + lane] = SP;
        p2Cnt[(size_t)blockIdx.x * 64 + lane] = CC;
    }
}

// ---- aux stage 2: 1 block over 64 partials ----
__global__ __launch_bounds__(256) void aux2_kernel(
    const float* __restrict__ p2Sum, const float* __restrict__ p2Cnt,
    float* __restrict__ aux_out, float scale)
{
    const int tid  = threadIdx.x;
    const int wv   = tid >> 6;       // 0..3
    const int lane = tid & 63;       // = expert id
    __shared__ float smem[2][4][64];

    float sp = 0.f, cc = 0.f;
#pragma unroll 1
    for (int b = wv * 16; b < wv * 16 + 16; ++b) {
        sp += p2Sum[(size_t)b * 64 + lane];
        cc += p2Cnt[(size_t)b * 64 + lane];
    }
    smem[0][wv][lane] = sp;
    smem[1][wv][lane] = cc;
    __syncthreads();
    if (wv == 0) {
        float SP = smem[0][0][lane] + smem[0][1][lane]
                 + smem[0][2][lane] + smem[0][3][lane];
        float CC = smem[1][0][lane] + smem[1][1][lane]
                 + smem[1][2][lane] + smem[1][3][lane];
        float prod = SP * CC;
#pragma unroll
        for (int off = 32; off; off >>= 1) prod += __shfl_xor(prod, off, 64);
        if (lane == 0) aux_out[0] = prod * scale;
    }
}

extern "C" void kernel_launch(void* const* d_in, const int* in_sizes, int n_in,
                              void* d_out, int out_size, void* d_ws, size_t ws_size,
                              hipStream_t stream) {
    const float* x  = (const float*)d_in[0];
    const float* Wg = (const float*)d_in[1];
    const int T = in_sizes[0] / DD;          // 16384

    float* out      = (float*)d_out;
    float* gate_out = out;                                // T*64
    float* idx_out  = out + (size_t)T * EE;               // T*2 (as float)
    float* aux_out  = idx_out + (size_t)T * 2;            // 1

    const int nblocks = T / BM;                           // 1024
    _Float16* wF = (_Float16*)d_ws;                       // 512 KB frag-linear
    float* pSum  = (float*)(wF + (size_t)64 * 8 * 512);   // 1024*64
    float* pCnt  = pSum + (size_t)nblocks * 64;           // 1024*64
    float* p2Sum = pCnt + (size_t)nblocks * 64;           // 64*64
    float* p2Cnt = p2Sum + 64 * 64;                       // 64*64

    wsplit_kernel<<<64, 256, 0, stream>>>(Wg, wF);
    gate_kernel<<<nblocks, 256, 0, stream>>>(x, wF, gate_out, idx_out, pSum, pCnt);

    const float scale = (float)EE / ((float)T * (float)T);
    aux1_kernel<<<64, 256, 0, stream>>>(pSum, pCnt, p2Sum, p2Cnt);
    aux2_kernel<<<1, 256, 0, stream>>>(p2Sum, p2Cnt, aux_out, scale);
}

// Round 25
// 56.074 us; speedup vs baseline: 1.6140x; 1.1093x over previous
//
#include <hip/hip_runtime.h>

// TopKGate via split-precision f16 MFMA (no fp32 MFMA on CDNA4):
//   x = xh + xl/4096, w = wh + wl/4096 (f16 planes, lo pre-scaled x4096)
//   logits = xh*wh + (xh*wl' + xl'*wh)/4096
// R25 = R17 (best: 53.9us) + EARLY W-LOADS: chunk c's 8 w-loads issued
// between WVM and BAR (latency overlaps barrier-wait + x ds_read + CVT);
// same-iteration live range (+16 VGPR, no ping-pong, no spill).
// Waves = 4 K-quarters; one x->f16 CVT per element; BM=16; grid 1024;
// NBUF=3; one barrier per chunk was R19 (neutral) - keep R17's two.

typedef __attribute__((ext_vector_type(8))) _Float16 half8;
typedef __attribute__((ext_vector_type(4))) float f32x4;

constexpr int DD  = 2048;
constexpr int EE  = 64;
constexpr int BM  = 16;          // tokens per block
constexpr int BK  = 128;         // k per staged chunk (each wave: 32-k quarter)
constexpr int NCH = DD / BK;     // 16 chunks

#define WVM(N) asm volatile("s_waitcnt vmcnt(" #N ")" ::: "memory")
#define BAR()  asm volatile("s_barrier" ::: "memory")

// ---- pre-kernel (R15-proven): Wg[2048][64] -> fragment-linear wF ----
// wF[(kc*8 + t*2 + p)*512 + l*8 + j] = plane_p( Wg[kc*32+(l>>4)*8+j][t*16+(l&15)] )
__global__ __launch_bounds__(256) void wsplit_kernel(
    const float* __restrict__ Wg, _Float16* __restrict__ wF)
{
    __shared__ float xl[32][65];
    const int tid = threadIdx.x;
    const int kc  = blockIdx.x;          // 64 blocks, 32 k's each
    const int k0  = kc * 32;
#pragma unroll
    for (int r = 0; r < 2; ++r) {
        int slot = tid + r * 256;        // float4 slots 0..511
        int row = slot >> 4, c4 = (slot & 15) << 2;
        *(float4*)&xl[row][c4] = *(const float4*)&Wg[(size_t)(k0 + row) * EE + c4];
    }
    __syncthreads();
    const int t = tid >> 6, l = tid & 63;
    const int e  = t * 16 + (l & 15);
    const int kl = (l >> 4) * 8;
    half8 hh, ll;
#pragma unroll
    for (int j = 0; j < 8; ++j) {
        float v = xl[kl + j][e];
        _Float16 h = (_Float16)v;
        hh[j] = h;
        ll[j] = (_Float16)((v - (float)h) * 4096.f);
    }
    const size_t base = (size_t)(kc * 8 + t * 2) * 512 + (size_t)l * 8;
    *(half8*)&wF[base]       = hh;       // hi plane
    *(half8*)&wF[base + 512] = ll;       // lo plane
}

__global__ __launch_bounds__(256, 4) void gate_kernel(
    const float* __restrict__ x, const _Float16* __restrict__ wF,
    float* __restrict__ gate_out, float* __restrict__ idx_out,
    float* __restrict__ pSum, float* __restrict__ pCnt)
{
    __shared__ __align__(16) union {
        float xs[3][BM][BK];                               // 24 KB staging
        struct { float red[4][BM][68]; float auxsm[2][4][64]; } ep; // 19.5 KB
    } sm;

    const int tid  = threadIdx.x;
    const int kq   = tid >> 6;           // wave = K-quarter of chunk (32 k's)
    const int lane = tid & 63;
    const size_t tok0 = (size_t)blockIdx.x * BM;
    const float* xg = x + tok0 * DD;

    // ---- x staging: 2 dwordx4 DMA per thread per chunk, 32B source-XOR ----
    auto stageX = [&](int buf, int c) {
#pragma unroll
        for (int r = 0; r < 2; ++r) {
            int slot = tid + r * 256;            // float4 slot 0..511
            int row  = slot >> 5;                // 0..15
            int cb   = (slot & 31) << 4;         // dest byte 0..511
            int sb   = cb ^ ((row & 7) << 5);    // source-swizzled byte
            __builtin_amdgcn_global_load_lds(
                xg + (size_t)row * DD + c * BK + (sb >> 2),
                &sm.xs[buf][row][cb >> 2], 16, 0, 0);
        }
    };

    f32x4 aH[4], aL[4];
#pragma unroll
    for (int t = 0; t < 4; ++t) {
        aH[t] = (f32x4){0.f, 0.f, 0.f, 0.f};
        aL[t] = (f32x4){0.f, 0.f, 0.f, 0.f};
    }

    const int rrow = lane & 15;          // token row
    const int rb   = (kq * 128 + ((lane >> 4) * 32)) ^ ((rrow & 7) << 5);

    // prologue: 2 stages in flight
    stageX(0, 0);
    stageX(1, 1);

#pragma unroll 1
    for (int c = 0; c < NCH; ++c) {
        if (c < NCH - 1) { WVM(2); } else { WVM(0); }  // stage(c) landed
        // ---- EARLY w-loads for chunk c: issue before the barrier so L2
        // latency hides under barrier-wait + x ds_read + CVT ----
        const _Float16* wb = wF + (size_t)(c * 4 + kq) * 4096 + (size_t)lane * 8;
        half8 wh[4], wl[4];
#pragma unroll
        for (int t = 0; t < 4; ++t) {
            wh[t] = *(const half8*)(wb + (t * 2) * 512);
            wl[t] = *(const half8*)(wb + (t * 2 + 1) * 512);
        }
        BAR();                                   // chunk c staged, all waves
        {
            // x fragment: one 8-float read, split once
            const float* p = (const float*)((const char*)&sm.xs[c % 3][rrow][0] + rb);
            float4 xa = *(const float4*)p;
            float4 xb = *(const float4*)(p + 4);
            half8 ah, al;
            {
                float v;
                v = xa.x; { _Float16 h=(_Float16)v; ah[0]=h; al[0]=(_Float16)((v-(float)h)*4096.f); }
                v = xa.y; { _Float16 h=(_Float16)v; ah[1]=h; al[1]=(_Float16)((v-(float)h)*4096.f); }
                v = xa.z; { _Float16 h=(_Float16)v; ah[2]=h; al[2]=(_Float16)((v-(float)h)*4096.f); }
                v = xa.w; { _Float16 h=(_Float16)v; ah[3]=h; al[3]=(_Float16)((v-(float)h)*4096.f); }
                v = xb.x; { _Float16 h=(_Float16)v; ah[4]=h; al[4]=(_Float16)((v-(float)h)*4096.f); }
                v = xb.y; { _Float16 h=(_Float16)v; ah[5]=h; al[5]=(_Float16)((v-(float)h)*4096.f); }
                v = xb.z; { _Float16 h=(_Float16)v; ah[6]=h; al[6]=(_Float16)((v-(float)h)*4096.f); }
                v = xb.w; { _Float16 h=(_Float16)v; ah[7]=h; al[7]=(_Float16)((v-(float)h)*4096.f); }
            }
#pragma unroll
            for (int t = 0; t < 4; ++t) {
                aH[t] = __builtin_amdgcn_mfma_f32_16x16x32_f16(ah, wh[t], aH[t], 0, 0, 0);
                aL[t] = __builtin_amdgcn_mfma_f32_16x16x32_f16(ah, wl[t], aL[t], 0, 0, 0);
                aL[t] = __builtin_amdgcn_mfma_f32_16x16x32_f16(al, wh[t], aL[t], 0, 0, 0);
            }
        }
        BAR();                                   // all waves done reading buf
        if (c + 2 < NCH) stageX((c + 2) % 3, c + 2);
    }

    // ---- K-partials -> LDS (m89-verified C layout), combine planes ----
    __syncthreads();
    const float inv = 1.f / 4096.f;
#pragma unroll
    for (int e = 0; e < 4; ++e) {
        const int row = (lane >> 4) * 4 + e;     // token 0..15
#pragma unroll
        for (int t = 0; t < 4; ++t)
            sm.ep.red[kq][row][t * 16 + (lane & 15)] = aH[t][e] + aL[t][e] * inv;
    }
    __syncthreads();

    // ---- epilogue: wave kq -> tokens [kq*4, kq*4+4); lane = expert ----
    float sumP_acc = 0.f;
    float cnt_acc  = 0.f;
#pragma unroll 1
    for (int tt = 0; tt < 4; ++tt) {
        const int tl = kq * 4 + tt;
        const size_t t = tok0 + tl;
        float v = (sm.ep.red[0][tl][lane] + sm.ep.red[1][tl][lane])
                + (sm.ep.red[2][tl][lane] + sm.ep.red[3][tl][lane]);

        float m = v;
#pragma unroll
        for (int off = 32; off; off >>= 1) m = fmaxf(m, __shfl_xor(m, off, 64));
        float p = expf(v - m);
        float s = p;
#pragma unroll
        for (int off = 32; off; off >>= 1) s += __shfl_xor(s, off, 64);
        float prob = p / s;
        sumP_acc += prob;

        // top-1 (ties -> lowest index, matches lax.top_k)
        float bv = prob; int bi = lane;
#pragma unroll
        for (int off = 32; off; off >>= 1) {
            float ov = __shfl_xor(bv, off, 64);
            int   oi = __shfl_xor(bi, off, 64);
            if (ov > bv || (ov == bv && oi < bi)) { bv = ov; bi = oi; }
        }
        // top-2
        float v2 = (lane == bi) ? -1.f : prob;
        float bv2 = v2; int bi2 = lane;
#pragma unroll
        for (int off = 32; off; off >>= 1) {
            float ov = __shfl_xor(bv2, off, 64);
            int   oi = __shfl_xor(bi2, off, 64);
            if (ov > bv2 || (ov == bv2 && oi < bi2)) { bv2 = ov; bi2 = oi; }
        }

        float denom = bv + bv2;
        float g1 = bv / denom, g2 = bv2 / denom;
        float g = (lane == bi) ? g1 : ((lane == bi2) ? g2 : 0.f);
        gate_out[t * EE + lane] = g;
        if (lane == 0) {
            idx_out[2 * t]     = (float)bi;
            idx_out[2 * t + 1] = (float)bi2;
        }
        cnt_acc += (lane == bi)  ? 1.f : 0.f;
        cnt_acc += (lane == bi2) ? 1.f : 0.f;
    }

    // ---- per-block aux partials (deterministic) ----
    sm.ep.auxsm[0][kq][lane] = sumP_acc;
    sm.ep.auxsm[1][kq][lane] = cnt_acc;
    __syncthreads();
    if (kq == 0) {
        float sp = 0.f, c2 = 0.f;
#pragma unroll
        for (int w = 0; w < 4; ++w) {
            sp += sm.ep.auxsm[0][w][lane];
            c2 += sm.ep.auxsm[1][w][lane];
        }
        pSum[(size_t)blockIdx.x * 64 + lane] = sp;
        pCnt[(size_t)blockIdx.x * 64 + lane] = c2;
    }
}

// parallel aux reduction: 1024 threads (16 waves), 4-deep ILP + LDS reduce
__global__ __launch_bounds__(1024) void aux_kernel(
    const float* __restrict__ pSum, const float* __restrict__ pCnt,
    float* __restrict__ aux_out, int nblocks, float scale)
{
    const int tid  = threadIdx.x;
    const int wv   = tid >> 6;       // 0..15
    const int lane = tid & 63;       // = expert id
    __shared__ float smem[2][16][64];

    float sp[4] = {0.f, 0.f, 0.f, 0.f};
    float cc[4] = {0.f, 0.f, 0.f, 0.f};
    for (int b = wv * 4; b < nblocks; b += 64) {
#pragma unroll
        for (int u = 0; u < 4; ++u) {
            sp[u] += pSum[(size_t)(b + u) * 64 + lane];
            cc[u] += pCnt[(size_t)(b + u) * 64 + lane];
        }
    }
    smem[0][wv][lane] = (sp[0] + sp[1]) + (sp[2] + sp[3]);
    smem[1][wv][lane] = (cc[0] + cc[1]) + (cc[2] + cc[3]);
    __syncthreads();
    if (wv == 0) {
        float SP = 0.f, C = 0.f;
#pragma unroll
        for (int w = 0; w < 16; ++w) {
            SP += smem[0][w][lane];
            C  += smem[1][w][lane];
        }
        float prod = SP * C;
#pragma unroll
        for (int off = 32; off; off >>= 1) prod += __shfl_xor(prod, off, 64);
        if (lane == 0) aux_out[0] = prod * scale;
    }
}

extern "C" void kernel_launch(void* const* d_in, const int* in_sizes, int n_in,
                              void* d_out, int out_size, void* d_ws, size_t ws_size,
                              hipStream_t stream) {
    const float* x  = (const float*)d_in[0];
    const float* Wg = (const float*)d_in[1];
    const int T = in_sizes[0] / DD;          // 16384

    float* out      = (float*)d_out;
    float* gate_out = out;                                // T*64
    float* idx_out  = out + (size_t)T * EE;               // T*2 (as float)
    float* aux_out  = idx_out + (size_t)T * 2;            // 1

    const int nblocks = T / BM;                           // 1024
    _Float16* wF = (_Float16*)d_ws;                       // 512 KB frag-linear
    float* pSum = (float*)(wF + (size_t)64 * 8 * 512);    // nblocks*64
    float* pCnt = pSum + (size_t)nblocks * 64;            // nblocks*64

    wsplit_kernel<<<64, 256, 0, stream>>>(Wg, wF);
    gate_kernel<<<nblocks, 256, 0, stream>>>(x, wF, gate_out, idx_out, pSum, pCnt);

    const float scale = (float)EE / ((float)T * (float)T);
    aux_kernel<<<1, 1024, 0, stream>>>(pSum, pCnt, aux_out, nblocks, scale);
}